// Round 3
// baseline (199.231 us; speedup 1.0000x reference)
//
#include <hip/hip_runtime.h>
#include <hip/hip_bf16.h>

#define BATCH 16384
#define FIN   768
#define FOUT  512

#define BM 128
#define BN 128
#define BK 32
#define LDK 40   // bf16 elems padded stride (80 B): <=2-way LDS conflicts, keeps 16B align
#define NT (FIN / BK)   // 24 K-tiles

typedef __attribute__((ext_vector_type(8))) short short8;
typedef __attribute__((ext_vector_type(4))) float floatx4;

// packed fp32x2 -> bf16x2, round-to-nearest-even (gfx940+ VOP3)
__device__ __forceinline__ unsigned int cvt_pk_bf16(float a, float b) {
    unsigned int r;
    asm("v_cvt_pk_bf16_f32 %0, %1, %2" : "=v"(r) : "v"(a), "v"(b));
    return r;
}

// One block: 128 rows (one perspective) x 128 features, K-loop over 768,
// double-buffered LDS + register prefetch. Epilogue: h = clip(acc+b1,0,1);
// partial = sum_cols h*W2; quad shuffle-reduce -> atomicAdd ws[row].
__global__ __launch_bounds__(256) void pn_gemm(
    const float* __restrict__ stm, const float* __restrict__ nstm,
    const float* __restrict__ W1, const float* __restrict__ b1,
    const float* __restrict__ W2, float* __restrict__ ws)
{
    __shared__ __align__(16) unsigned short As[2][BM * LDK];
    __shared__ __align__(16) unsigned short Bs[2][BN * LDK];

    const int tid  = threadIdx.x;
    const int lane = tid & 63;
    const int wave = tid >> 6;
    const int wm   = wave >> 1;
    const int wn   = wave & 1;
    const int quad = lane >> 4;
    const int l16  = lane & 15;

    // XCD swizzle: 4 col-tiles of one row-tile -> ids congruent mod 8 (same XCD)
    const int id = blockIdx.x;            // 0..1023
    const int g  = id >> 5;               // 32-block super-group = 8 rowTiles x 4 colTiles
    const int w5 = id & 31;
    const int rowTileIdx = g * 8 + (w5 & 7);   // 0..255
    const int colTile    = (w5 >> 3) * BN;     // 0,128,256,384
    const int rowTile    = rowTileIdx * BM;

    const int p = (rowTile >= BATCH) ? 1 : 0;
    const float* __restrict__ X = p ? nstm : stm;
    const int rowOff = rowTile - p * BATCH;

    // per-thread staging geometry: idx = tid + i*256; row = idx>>3 (0..127), p4 = idx&7
    const int srow = tid >> 3;   // base row (0..31), +32 per i
    const int sp4  = tid & 7;    // float4 slot within 32-k chunk

    const float* aPtr = X  + (size_t)(rowOff  + srow) * FIN + sp4 * 4;
    const float* bPtr = W1 + (size_t)(colTile + srow) * FIN + sp4 * 4;

    floatx4 acc[4][4];
    #pragma unroll
    for (int i = 0; i < 4; ++i)
        #pragma unroll
        for (int j = 0; j < 4; ++j)
            acc[i][j] = (floatx4)0.0f;

    float4 av[4], bv[4];

    // ---- prologue: load + store tile 0 into buffer 0
    #pragma unroll
    for (int i = 0; i < 4; ++i) {
        av[i] = *(const float4*)(aPtr + (size_t)(i * 32) * FIN);
        bv[i] = *(const float4*)(bPtr + (size_t)(i * 32) * FIN);
    }
    #pragma unroll
    for (int i = 0; i < 4; ++i) {
        uint2 pa, pb;
        pa.x = cvt_pk_bf16(av[i].x, av[i].y);
        pa.y = cvt_pk_bf16(av[i].z, av[i].w);
        pb.x = cvt_pk_bf16(bv[i].x, bv[i].y);
        pb.y = cvt_pk_bf16(bv[i].z, bv[i].w);
        *(uint2*)(&As[0][(srow + i * 32) * LDK + sp4 * 4]) = pa;
        *(uint2*)(&Bs[0][(srow + i * 32) * LDK + sp4 * 4]) = pb;
    }
    __syncthreads();

    #pragma unroll 2
    for (int t = 1; t < NT; ++t) {
        const int cur = (t - 1) & 1;
        const int nxt = t & 1;
        const int kt  = t * BK;

        // prefetch next tile into registers (latency overlapped with MFMAs below)
        #pragma unroll
        for (int i = 0; i < 4; ++i) {
            av[i] = *(const float4*)(aPtr + kt + (size_t)(i * 32) * FIN);
            bv[i] = *(const float4*)(bPtr + kt + (size_t)(i * 32) * FIN);
        }

        // MFMA on current buffer
        {
            short8 af[4], bfr[4];
            #pragma unroll
            for (int mi = 0; mi < 4; ++mi)
                af[mi] = *(const short8*)(&As[cur][(wm * 64 + mi * 16 + l16) * LDK + quad * 8]);
            #pragma unroll
            for (int ni = 0; ni < 4; ++ni)
                bfr[ni] = *(const short8*)(&Bs[cur][(wn * 64 + ni * 16 + l16) * LDK + quad * 8]);
            #pragma unroll
            for (int mi = 0; mi < 4; ++mi)
                #pragma unroll
                for (int ni = 0; ni < 4; ++ni)
                    acc[mi][ni] = __builtin_amdgcn_mfma_f32_16x16x32_bf16(
                        af[mi], bfr[ni], acc[mi][ni], 0, 0, 0);
        }

        // convert + store prefetched tile into the other buffer
        #pragma unroll
        for (int i = 0; i < 4; ++i) {
            uint2 pa, pb;
            pa.x = cvt_pk_bf16(av[i].x, av[i].y);
            pa.y = cvt_pk_bf16(av[i].z, av[i].w);
            pb.x = cvt_pk_bf16(bv[i].x, bv[i].y);
            pb.y = cvt_pk_bf16(bv[i].z, bv[i].w);
            *(uint2*)(&As[nxt][(srow + i * 32) * LDK + sp4 * 4]) = pa;
            *(uint2*)(&Bs[nxt][(srow + i * 32) * LDK + sp4 * 4]) = pb;
        }
        __syncthreads();
    }

    // ---- last tile MFMA
    {
        const int cur = (NT - 1) & 1;
        short8 af[4], bfr[4];
        #pragma unroll
        for (int mi = 0; mi < 4; ++mi)
            af[mi] = *(const short8*)(&As[cur][(wm * 64 + mi * 16 + l16) * LDK + quad * 8]);
        #pragma unroll
        for (int ni = 0; ni < 4; ++ni)
            bfr[ni] = *(const short8*)(&Bs[cur][(wn * 64 + ni * 16 + l16) * LDK + quad * 8]);
        #pragma unroll
        for (int mi = 0; mi < 4; ++mi)
            #pragma unroll
            for (int ni = 0; ni < 4; ++ni)
                acc[mi][ni] = __builtin_amdgcn_mfma_f32_16x16x32_bf16(
                    af[mi], bfr[ni], acc[mi][ni], 0, 0, 0);
    }

    // ---- epilogue: C/D layout col = lane&15, row = quad*4 + reg
    float b1v[4], w2v[4];
    #pragma unroll
    for (int ni = 0; ni < 4; ++ni) {
        int col = colTile + wn * 64 + ni * 16 + l16;
        b1v[ni] = b1[col];
        w2v[ni] = W2[p * FOUT + col];
    }

    const int rBase = rowOff + wm * 64;
    #pragma unroll
    for (int mi = 0; mi < 4; ++mi) {
        #pragma unroll
        for (int r = 0; r < 4; ++r) {
            float s = 0.0f;
            #pragma unroll
            for (int ni = 0; ni < 4; ++ni) {
                float h = acc[mi][ni][r] + b1v[ni];
                h = fminf(fmaxf(h, 0.0f), 1.0f);
                s += h * w2v[ni];
            }
            s += __shfl_xor(s, 1);
            s += __shfl_xor(s, 2);
            s += __shfl_xor(s, 4);
            s += __shfl_xor(s, 8);
            if (l16 == 0) {
                atomicAdd(&ws[rBase + mi * 16 + quad * 4 + r], s);
            }
        }
    }
}

__global__ __launch_bounds__(256) void pn_finalize(
    const float* __restrict__ ws, const float* __restrict__ b2,
    float* __restrict__ out)
{
    int i = blockIdx.x * blockDim.x + threadIdx.x;
    float x = ws[i] + b2[0];
    out[i] = 1.0f / (1.0f + expf(-x));
}

extern "C" void kernel_launch(void* const* d_in, const int* in_sizes, int n_in,
                              void* d_out, int out_size, void* d_ws, size_t ws_size,
                              hipStream_t stream)
{
    (void)in_sizes; (void)n_in; (void)out_size; (void)ws_size;
    const float* stm  = (const float*)d_in[0];
    const float* nstm = (const float*)d_in[1];
    const float* W1   = (const float*)d_in[2];
    const float* b1   = (const float*)d_in[3];
    const float* W2   = (const float*)d_in[4];
    const float* b2   = (const float*)d_in[5];
    float* out = (float*)d_out;
    float* ws  = (float*)d_ws;

    hipMemsetAsync(ws, 0, BATCH * sizeof(float), stream);

    dim3 grid((FOUT / BN) * ((2 * BATCH) / BM));   // 1024 blocks, 1D for swizzle
    pn_gemm<<<grid, dim3(256), 0, stream>>>(stm, nstm, W1, b1, W2, ws);
    pn_finalize<<<dim3(BATCH / 256), dim3(256), 0, stream>>>(ws, b2, out);
}